// Round 2
// baseline (17216.121 us; speedup 1.0000x reference)
//
#include <hip/hip_runtime.h>

typedef _Float16 half2_t __attribute__((ext_vector_type(2)));
typedef _Float16 half4_t __attribute__((ext_vector_type(4)));
typedef _Float16 half8_t __attribute__((ext_vector_type(8)));
typedef float f32x4 __attribute__((ext_vector_type(4)));
typedef unsigned int u32;

#define BB 64
#define TT 2048
#define II 128
#define HH 256
#define CC 64
#define G3 (3*HH)          // 768
#define MTOT (BB*TT)       // 131072

static __device__ __forceinline__ float dot2f(half2_t a, half2_t b, float c) {
#if __has_builtin(__builtin_amdgcn_fdot2)
    return __builtin_amdgcn_fdot2(a, b, c, false);
#else
    return c + (float)a[0]*(float)b[0] + (float)a[1]*(float)b[1];
#endif
}

// ---------------------------------------------------------------------------
// Tiled GEMM: C[M,N] = A[M,K] @ W[N,K]^T + bias1 (+ bias2 for n<lim).
// f16 dot2 inner, fp32 accum. Unchanged from R1 except the second bias
// (folds b_hh into gx for the r/z gate rows).
// ---------------------------------------------------------------------------
template<typename AT, typename CT>
__global__ __launch_bounds__(256, 2)
void gemm_bt(const AT* __restrict__ A, const float* __restrict__ W,
             const float* __restrict__ bias1, const float* __restrict__ bias2,
             int lim, CT* __restrict__ Cout, int M, int N, int K)
{
    __shared__ half2_t As[128][17];   // 16 k-pairs + 1 pad
    __shared__ half2_t Bs[64][17];
    const int tid = threadIdx.x;
    const int m0 = blockIdx.y * 128;
    const int n0 = blockIdx.x * 64;
    const int mt = tid & 15;
    const int nt = tid >> 4;
    float acc[8][4] = {};

    for (int kc = 0; kc < K; kc += 32) {
        {   // A tile: 128 rows x 32 k
            const int row = tid >> 1;
            const int ko  = (tid & 1) * 16;
            const AT* src = A + (size_t)(m0 + row) * K + kc + ko;
            #pragma unroll
            for (int u = 0; u < 8; ++u)
                As[row][(ko >> 1) + u] =
                    half2_t{(_Float16)(float)src[2*u], (_Float16)(float)src[2*u+1]};
        }
        {   // B tile: 64 rows x 32 k (weights, fp32 -> f16)
            const int row = tid >> 2;
            const int ko  = (tid & 3) * 8;
            const float* src = W + (size_t)(n0 + row) * K + kc + ko;
            #pragma unroll
            for (int u = 0; u < 4; ++u)
                Bs[row][(ko >> 1) + u] =
                    half2_t{(_Float16)src[2*u], (_Float16)src[2*u+1]};
        }
        __syncthreads();
        #pragma unroll
        for (int kp = 0; kp < 16; ++kp) {
            half2_t av[8], bv[4];
            #pragma unroll
            for (int r = 0; r < 8; ++r) av[r] = As[mt*8 + r][kp];
            #pragma unroll
            for (int c = 0; c < 4; ++c) bv[c] = Bs[nt*4 + c][kp];
            #pragma unroll
            for (int r = 0; r < 8; ++r)
                #pragma unroll
                for (int c = 0; c < 4; ++c)
                    acc[r][c] = dot2f(av[r], bv[c], acc[r][c]);
        }
        __syncthreads();
    }
    #pragma unroll
    for (int r = 0; r < 8; ++r) {
        const int m = m0 + mt*8 + r;
        #pragma unroll
        for (int c = 0; c < 4; ++c) {
            const int n = n0 + nt*4 + c;
            float b = bias1[n] + ((bias2 && n < lim) ? bias2[n] : 0.f);
            Cout[(size_t)m * N + n] = (CT)(acc[r][c] + b);
        }
    }
}

// ---------------------------------------------------------------------------
// MFMA GRU scan. 16 WGs x 4 batches, 512 threads (8 waves).
// Per step per WG: W_hh·h via 48 MFMAs/wave (6 M-tiles x 8 k-blocks),
// A = W_hh stationary in regs (f16 frags), B = h from double-buffered LDS
// (8 ds_read_b128/wave, 4-way lane broadcast via bl&3). Wave w owns the
// (r,z,n) row-tile triples {2w, 2w+1} so gate math is in-lane:
// D layout col=lane&15 (batch), row=(lane>>4)*4+reg. One barrier per step.
// gx rows r/z carry b_ih+b_hh (folded in GEMM); n rows carry b_ih only,
// b_hh_n added here inside r*(.).
// ---------------------------------------------------------------------------
__global__ __launch_bounds__(512, 2)
void gru_scan_mfma(const _Float16* __restrict__ gx,   // [B,T,768]
                   const float* __restrict__ Whh,     // [768,256]
                   const float* __restrict__ bhh,     // [768]
                   _Float16* __restrict__ hout)       // [B,T,256]
{
    const int tid  = threadIdx.x;
    const int w    = tid >> 6;        // wave 0..7
    const int lane = tid & 63;
    const int bl   = lane & 15;       // MFMA col = batch lane
    const int q    = lane >> 4;       // quad
    const int grp  = blockIdx.x;      // 0..15
    const bool act = (bl < 4);
    const int batch = grp * 4 + (bl & 3);   // always valid; bl>=4 lanes duplicate

    // --- stationary A fragments: A[ti][gate][kb], lane holds W[tile16+bl][kb*32+q*8 ..+8]
    half8_t A[2][3][8];
    #pragma unroll
    for (int ti = 0; ti < 2; ++ti) {
        const int I = 2*w + ti;
        #pragma unroll
        for (int g = 0; g < 3; ++g) {
            const float* rowp = Whh + (size_t)(g*256 + I*16 + bl) * HH;
            #pragma unroll
            for (int kb = 0; kb < 8; ++kb) {
                const float* p = rowp + kb*32 + q*8;
                half8_t a;
                #pragma unroll
                for (int e = 0; e < 8; ++e) a[e] = (_Float16)p[e];
                A[ti][g][kb] = a;
            }
        }
    }
    // b_hh for n-gate rows of this lane
    float bhn[2][4];
    #pragma unroll
    for (int ti = 0; ti < 2; ++ti) {
        const int I = 2*w + ti;
        #pragma unroll
        for (int p = 0; p < 4; ++p)
            bhn[ti][p] = bhh[512 + I*16 + q*4 + p];
    }

    // h double buffer: [buf][batch(4)][272 f16] -> 8-bank shift/row, <=2-way aliasing
    __shared__ alignas(16) _Float16 h2[2][4][272];
    {
        _Float16* hz = &h2[0][0][0];
        for (int idx = tid; idx < 2*4*272; idx += 512) hz[idx] = (_Float16)0.f;
    }
    float hprev[2][4] = {};
    __syncthreads();

    const _Float16* gp = gx + (size_t)batch * TT * G3;
    _Float16* hp = hout + (size_t)batch * TT * HH;

    for (int t = 0; t < TT; ++t) {
        const int cur = t & 1, nxt = cur ^ 1;

        // gx loads for this step (consumed in epilogue; latency hidden by MFMAs)
        half4_t gr[2], gz[2], gn[2];
        #pragma unroll
        for (int ti = 0; ti < 2; ++ti) {
            const int g0 = (2*w + ti)*16 + 4*q;
            gr[ti] = *(const half4_t*)(gp + g0);
            gz[ti] = *(const half4_t*)(gp + 256 + g0);
            gn[ti] = *(const half4_t*)(gp + 512 + g0);
        }

        // MFMA phase: acc[ti][gate] over 8 k-blocks
        f32x4 acc[2][3];
        #pragma unroll
        for (int ti = 0; ti < 2; ++ti)
            #pragma unroll
            for (int g = 0; g < 3; ++g)
                acc[ti][g] = f32x4{0.f, 0.f, 0.f, 0.f};
        #pragma unroll
        for (int kb = 0; kb < 8; ++kb) {
            half8_t Bf = *(const half8_t*)&h2[cur][bl & 3][kb*32 + q*8];
            #pragma unroll
            for (int ti = 0; ti < 2; ++ti)
                #pragma unroll
                for (int g = 0; g < 3; ++g)
                    acc[ti][g] = __builtin_amdgcn_mfma_f32_16x16x32_f16(
                        A[ti][g][kb], Bf, acc[ti][g], 0, 0, 0);
        }

        // epilogue: gate math fully in-lane; rows = (2w+ti)*16 + 4q + p, col = batch
        #pragma unroll
        for (int ti = 0; ti < 2; ++ti) {
            half4_t hh;
            #pragma unroll
            for (int p = 0; p < 4; ++p) {
                const float xr = (float)gr[ti][p] + acc[ti][0][p];   // has b_ih+b_hh
                const float xz = (float)gz[ti][p] + acc[ti][1][p];   // has b_ih+b_hh
                const float qn = acc[ti][2][p] + bhn[ti][p];
                const float r  = 1.f / (1.f + __expf(-xr));
                const float z  = 1.f / (1.f + __expf(-xz));
                const float e  = __expf(2.f * ((float)gn[ti][p] + r * qn));
                const float n  = 1.f - 2.f / (e + 1.f);
                const float hnew = (1.f - z) * n + z * hprev[ti][p];
                hprev[ti][p] = hnew;
                hh[p] = (_Float16)hnew;
            }
            if (act) {
                const int row = (2*w + ti)*16 + 4*q;
                *(half4_t*)&h2[nxt][bl][row] = hh;
                *(half4_t*)(hp + row) = hh;
            }
        }
        __syncthreads();   // h2[nxt] visible; h2[cur] reads all done
        gp += G3;
        hp += HH;
    }
}

// ---------------------------------------------------------------------------
extern "C" void kernel_launch(void* const* d_in, const int* in_sizes, int n_in,
                              void* d_out, int out_size, void* d_ws, size_t ws_size,
                              hipStream_t stream) {
    const float* x    = (const float*)d_in[0];
    const float* Wih0 = (const float*)d_in[1];
    const float* Whh0 = (const float*)d_in[2];
    const float* bih0 = (const float*)d_in[3];
    const float* bhh0 = (const float*)d_in[4];
    const float* Wih1 = (const float*)d_in[5];
    const float* Whh1 = (const float*)d_in[6];
    const float* bih1 = (const float*)d_in[7];
    const float* bhh1 = (const float*)d_in[8];
    const float* fcw  = (const float*)d_in[9];
    const float* fcb  = (const float*)d_in[10];
    float* out = (float*)d_out;

    // workspace: gx buffer (192 MB, reused for both layers) + h buffer (64 MB)
    _Float16* gxbuf = (_Float16*)d_ws;
    _Float16* hbuf  = (_Float16*)((char*)d_ws + (size_t)MTOT * G3 * sizeof(_Float16));

    const dim3 blk(256);
    // 1) gx0 = x @ W_ih0^T + (b_ih0 + b_hh0 for r/z rows)
    gemm_bt<float, _Float16><<<dim3(G3/64, MTOT/128), blk, 0, stream>>>(
        x, Wih0, bih0, bhh0, 512, gxbuf, MTOT, G3, II);
    // 2) scan layer 0 -> h0
    gru_scan_mfma<<<dim3(16), dim3(512), 0, stream>>>(gxbuf, Whh0, bhh0, hbuf);
    // 3) gx1 = h0 @ W_ih1^T + (b_ih1 + b_hh1 for r/z rows)
    gemm_bt<_Float16, _Float16><<<dim3(G3/64, MTOT/128), blk, 0, stream>>>(
        hbuf, Wih1, bih1, bhh1, 512, gxbuf, MTOT, G3, HH);
    // 4) scan layer 1 -> h1
    gru_scan_mfma<<<dim3(16), dim3(512), 0, stream>>>(gxbuf, Whh1, bhh1, hbuf);
    // 5) out = h1 @ fc_w^T + fc_b
    gemm_bt<_Float16, float><<<dim3(CC/64, MTOT/128), blk, 0, stream>>>(
        hbuf, fcw, fcb, nullptr, 0, out, MTOT, CC, HH);
}

// Round 3
// 16778.967 us; speedup vs baseline: 1.0261x; 1.0261x over previous
//
#include <hip/hip_runtime.h>

typedef _Float16 half2_t __attribute__((ext_vector_type(2)));
typedef _Float16 half4_t __attribute__((ext_vector_type(4)));
typedef _Float16 half8_t __attribute__((ext_vector_type(8)));
typedef float f32x4 __attribute__((ext_vector_type(4)));

#define BB 64
#define TT 2048
#define II 128
#define HH 256
#define CC 64
#define G3 (3*HH)          // 768
#define MTOT (BB*TT)       // 131072

static __device__ __forceinline__ float dot2f(half2_t a, half2_t b, float c) {
#if __has_builtin(__builtin_amdgcn_fdot2)
    return __builtin_amdgcn_fdot2(a, b, c, false);
#else
    return c + (float)a[0]*(float)b[0] + (float)a[1]*(float)b[1];
#endif
}

// ---------------------------------------------------------------------------
// Tiled GEMM: C[M,N] = A[M,K] @ W[N,K]^T + bias1 (+ bias2 for n<lim).
// f16 dot2 inner, fp32 accum. Unchanged from R1/R2 (verified).
// ---------------------------------------------------------------------------
template<typename AT, typename CT>
__global__ __launch_bounds__(256, 2)
void gemm_bt(const AT* __restrict__ A, const float* __restrict__ W,
             const float* __restrict__ bias1, const float* __restrict__ bias2,
             int lim, CT* __restrict__ Cout, int M, int N, int K)
{
    __shared__ half2_t As[128][17];
    __shared__ half2_t Bs[64][17];
    const int tid = threadIdx.x;
    const int m0 = blockIdx.y * 128;
    const int n0 = blockIdx.x * 64;
    const int mt = tid & 15;
    const int nt = tid >> 4;
    float acc[8][4] = {};

    for (int kc = 0; kc < K; kc += 32) {
        {
            const int row = tid >> 1;
            const int ko  = (tid & 1) * 16;
            const AT* src = A + (size_t)(m0 + row) * K + kc + ko;
            #pragma unroll
            for (int u = 0; u < 8; ++u)
                As[row][(ko >> 1) + u] =
                    half2_t{(_Float16)(float)src[2*u], (_Float16)(float)src[2*u+1]};
        }
        {
            const int row = tid >> 2;
            const int ko  = (tid & 3) * 8;
            const float* src = W + (size_t)(n0 + row) * K + kc + ko;
            #pragma unroll
            for (int u = 0; u < 4; ++u)
                Bs[row][(ko >> 1) + u] =
                    half2_t{(_Float16)src[2*u], (_Float16)src[2*u+1]};
        }
        __syncthreads();
        #pragma unroll
        for (int kp = 0; kp < 16; ++kp) {
            half2_t av[8], bv[4];
            #pragma unroll
            for (int r = 0; r < 8; ++r) av[r] = As[mt*8 + r][kp];
            #pragma unroll
            for (int c = 0; c < 4; ++c) bv[c] = Bs[nt*4 + c][kp];
            #pragma unroll
            for (int r = 0; r < 8; ++r)
                #pragma unroll
                for (int c = 0; c < 4; ++c)
                    acc[r][c] = dot2f(av[r], bv[c], acc[r][c]);
        }
        __syncthreads();
    }
    #pragma unroll
    for (int r = 0; r < 8; ++r) {
        const int m = m0 + mt*8 + r;
        #pragma unroll
        for (int c = 0; c < 4; ++c) {
            const int n = n0 + nt*4 + c;
            float b = bias1[n] + ((bias2 && n < lim) ? bias2[n] : 0.f);
            Cout[(size_t)m * N + n] = (CT)(acc[r][c] + b);
        }
    }
}

// ---------------------------------------------------------------------------
// MFMA GRU scan, register-budget-safe version.
// 16 WGs x 4 batches, 512 threads (8 waves, 2/SIMD -> 256 unified regs/wave).
// Register tally: A-frags 192 (AGPR-eligible, MFMA reads AGPR natively) +
// acc 24 + gx 12 (software-prefetched 1 step ahead, reloaded into the SAME
// regs after last use) + bhn 4 (f16-packed) + hprev 4 (f16) + 2 ptrs + temps
// ~ 249 <= 256. No __syncthreads in the loop: raw "lgkmcnt(0); s_barrier"
// drains LDS only, so hout stores and gx prefetch loads stay in flight
// across the barrier (no per-step vmcnt(0) serialization).
// ---------------------------------------------------------------------------
__global__ __launch_bounds__(512, 2)
void gru_scan_mfma(const _Float16* __restrict__ gx,   // [B,T,768]
                   const float* __restrict__ Whh,     // [768,256]
                   const float* __restrict__ bhh,     // [768]
                   _Float16* __restrict__ hout)       // [B,T,256]
{
    const int tid  = threadIdx.x;
    const int w    = tid >> 6;        // wave 0..7
    const int lane = tid & 63;
    const int bl   = lane & 15;       // MFMA row-in-tile (A) / batch col (B,D)
    const int q    = lane >> 4;       // quad
    const int grp  = blockIdx.x;      // 0..15
    const bool act = (bl < 4);
    const int batch = grp * 4 + (bl & 3);

    // --- stationary A fragments: lane holds W[g*256 + (2w+ti)*16 + bl][kb*32+q*8 ..+8]
    half8_t A[2][3][8];
    #pragma unroll
    for (int ti = 0; ti < 2; ++ti) {
        const int I = 2*w + ti;
        #pragma unroll
        for (int g = 0; g < 3; ++g) {
            const float* rowp = Whh + (size_t)(g*256 + I*16 + bl) * HH;
            #pragma unroll
            for (int kb = 0; kb < 8; ++kb) {
                const float* p = rowp + kb*32 + q*8;
                half8_t a;
                #pragma unroll
                for (int e = 0; e < 8; ++e) a[e] = (_Float16)p[e];
                A[ti][g][kb] = a;
            }
        }
    }
    // b_hh for n-gate rows of this lane, packed f16 (4 regs)
    half4_t bhn2[2];
    #pragma unroll
    for (int ti = 0; ti < 2; ++ti) {
        half4_t v;
        #pragma unroll
        for (int p = 0; p < 4; ++p)
            v[p] = (_Float16)bhh[512 + (2*w + ti)*16 + 4*q + p];
        bhn2[ti] = v;
    }

    // h double buffer: [buf][batch(4)][272 f16] (272 = 17*16 -> <=2-way bank alias)
    __shared__ alignas(16) _Float16 h2[2][4][272];
    for (int idx = tid; idx < 2*4*272; idx += 512) (&h2[0][0][0])[idx] = (_Float16)0.f;

    half4_t hprev[2] = {half4_t{0,0,0,0}, half4_t{0,0,0,0}};

    // gx pointer: base includes this lane's row0 = 2w*16 + 4q; the six values
    // are at f16-offsets {0,32} + gate*256 -> 8-byte loads with imm offsets.
    const _Float16* gp = gx + (size_t)batch * TT * G3 + (2*w)*16 + 4*q;
    _Float16* hp = hout + (size_t)batch * TT * HH + (2*w)*16 + 4*q;

    // prefetch gx for step 0
    half4_t gr[2], gz[2], gn[2];
    #pragma unroll
    for (int ti = 0; ti < 2; ++ti) {
        gr[ti] = *(const half4_t*)(gp + ti*16);
        gz[ti] = *(const half4_t*)(gp + 256 + ti*16);
        gn[ti] = *(const half4_t*)(gp + 512 + ti*16);
    }
    gp += G3;

    __syncthreads();   // h2 zeros visible (one-time full barrier is fine)

    for (int t = 0; t < TT; ++t) {
        const int cur = t & 1, nxt = cur ^ 1;

        // MFMA phase: 48 MFMAs/wave, B = h broadcast from LDS
        f32x4 acc[2][3];
        #pragma unroll
        for (int ti = 0; ti < 2; ++ti)
            #pragma unroll
            for (int g = 0; g < 3; ++g)
                acc[ti][g] = f32x4{0.f, 0.f, 0.f, 0.f};
        #pragma unroll
        for (int kb = 0; kb < 8; ++kb) {
            half8_t Bf = *(const half8_t*)&h2[cur][bl & 3][kb*32 + q*8];
            #pragma unroll
            for (int ti = 0; ti < 2; ++ti)
                #pragma unroll
                for (int g = 0; g < 3; ++g)
                    acc[ti][g] = __builtin_amdgcn_mfma_f32_16x16x32_f16(
                        A[ti][g][kb], Bf, acc[ti][g], 0, 0, 0);
        }

        // epilogue: in-lane gate math (D: col=lane&15=batch, row=q*4+reg)
        #pragma unroll
        for (int ti = 0; ti < 2; ++ti) {
            half4_t hh;
            #pragma unroll
            for (int p = 0; p < 4; ++p) {
                const float xr = (float)gr[ti][p] + acc[ti][0][p];   // b_ih+b_hh folded
                const float xz = (float)gz[ti][p] + acc[ti][1][p];   // b_ih+b_hh folded
                const float qn = acc[ti][2][p] + (float)bhn2[ti][p];
                const float r  = 1.f / (1.f + __expf(-xr));
                const float z  = 1.f / (1.f + __expf(-xz));
                const float e  = __expf(2.f * ((float)gn[ti][p] + r * qn));
                const float n  = 1.f - 2.f / (e + 1.f);
                const float hnew = (1.f - z) * n + z * (float)hprev[ti][p];
                hprev[ti][p] = (_Float16)hnew;
                hh[p] = (_Float16)hnew;
            }
            if (act) {
                const int row = (2*w + ti)*16 + 4*q;
                *(half4_t*)&h2[nxt][bl][row] = hh;      // LDS (lgkm)
                *(half4_t*)(hp + ti*16) = hh;           // global store, not waited
            }
        }
        hp += HH;

        // reload gx for step t+1 into the SAME registers (after last use).
        // Last iteration overreads into hbuf region of d_ws -- harmless.
        #pragma unroll
        for (int ti = 0; ti < 2; ++ti) {
            gr[ti] = *(const half4_t*)(gp + ti*16);
            gz[ti] = *(const half4_t*)(gp + 256 + ti*16);
            gn[ti] = *(const half4_t*)(gp + 512 + ti*16);
        }
        gp += G3;

        // LDS-only barrier: do NOT drain vmcnt (stores + gx prefetch fly free)
        asm volatile("s_waitcnt lgkmcnt(0)\n\ts_barrier" ::: "memory");
    }
}

// ---------------------------------------------------------------------------
extern "C" void kernel_launch(void* const* d_in, const int* in_sizes, int n_in,
                              void* d_out, int out_size, void* d_ws, size_t ws_size,
                              hipStream_t stream) {
    const float* x    = (const float*)d_in[0];
    const float* Wih0 = (const float*)d_in[1];
    const float* Whh0 = (const float*)d_in[2];
    const float* bih0 = (const float*)d_in[3];
    const float* bhh0 = (const float*)d_in[4];
    const float* Wih1 = (const float*)d_in[5];
    const float* Whh1 = (const float*)d_in[6];
    const float* bih1 = (const float*)d_in[7];
    const float* bhh1 = (const float*)d_in[8];
    const float* fcw  = (const float*)d_in[9];
    const float* fcb  = (const float*)d_in[10];
    float* out = (float*)d_out;

    _Float16* gxbuf = (_Float16*)d_ws;
    _Float16* hbuf  = (_Float16*)((char*)d_ws + (size_t)MTOT * G3 * sizeof(_Float16));

    const dim3 blk(256);
    // 1) gx0 = x @ W_ih0^T + (b_ih0 + b_hh0 for r/z rows)
    gemm_bt<float, _Float16><<<dim3(G3/64, MTOT/128), blk, 0, stream>>>(
        x, Wih0, bih0, bhh0, 512, gxbuf, MTOT, G3, II);
    // 2) scan layer 0 -> h0
    gru_scan_mfma<<<dim3(16), dim3(512), 0, stream>>>(gxbuf, Whh0, bhh0, hbuf);
    // 3) gx1 = h0 @ W_ih1^T + (b_ih1 + b_hh1 for r/z rows)
    gemm_bt<_Float16, _Float16><<<dim3(G3/64, MTOT/128), blk, 0, stream>>>(
        hbuf, Wih1, bih1, bhh1, 512, gxbuf, MTOT, G3, HH);
    // 4) scan layer 1 -> h1
    gru_scan_mfma<<<dim3(16), dim3(512), 0, stream>>>(gxbuf, Whh1, bhh1, hbuf);
    // 5) out = h1 @ fc_w^T + fc_b
    gemm_bt<_Float16, float><<<dim3(CC/64, MTOT/128), blk, 0, stream>>>(
        hbuf, fcw, fcb, nullptr, 0, out, MTOT, CC, HH);
}

// Round 4
// 16334.818 us; speedup vs baseline: 1.0540x; 1.0272x over previous
//
#include <hip/hip_runtime.h>

typedef _Float16 half2_t __attribute__((ext_vector_type(2)));
typedef _Float16 half4_t __attribute__((ext_vector_type(4)));
typedef _Float16 half8_t __attribute__((ext_vector_type(8)));
typedef float f32x4 __attribute__((ext_vector_type(4)));

#define BB 64
#define TT 2048
#define II 128
#define HH 256
#define CC 64
#define G3 (3*HH)          // 768
#define MTOT (BB*TT)       // 131072

static __device__ __forceinline__ float dot2f(half2_t a, half2_t b, float c) {
#if __has_builtin(__builtin_amdgcn_fdot2)
    return __builtin_amdgcn_fdot2(a, b, c, false);
#else
    return c + (float)a[0]*(float)b[0] + (float)a[1]*(float)b[1];
#endif
}

// ---------------------------------------------------------------------------
// Tiled GEMM: C[M,N] = A[M,K] @ W[N,K]^T + bias1 (+ bias2 for n<lim).
// f16 dot2 inner, fp32 accum. Unchanged (verified R1-R3).
// ---------------------------------------------------------------------------
template<typename AT, typename CT>
__global__ __launch_bounds__(256, 2)
void gemm_bt(const AT* __restrict__ A, const float* __restrict__ W,
             const float* __restrict__ bias1, const float* __restrict__ bias2,
             int lim, CT* __restrict__ Cout, int M, int N, int K)
{
    __shared__ half2_t As[128][17];
    __shared__ half2_t Bs[64][17];
    const int tid = threadIdx.x;
    const int m0 = blockIdx.y * 128;
    const int n0 = blockIdx.x * 64;
    const int mt = tid & 15;
    const int nt = tid >> 4;
    float acc[8][4] = {};

    for (int kc = 0; kc < K; kc += 32) {
        {
            const int row = tid >> 1;
            const int ko  = (tid & 1) * 16;
            const AT* src = A + (size_t)(m0 + row) * K + kc + ko;
            #pragma unroll
            for (int u = 0; u < 8; ++u)
                As[row][(ko >> 1) + u] =
                    half2_t{(_Float16)(float)src[2*u], (_Float16)(float)src[2*u+1]};
        }
        {
            const int row = tid >> 2;
            const int ko  = (tid & 3) * 8;
            const float* src = W + (size_t)(n0 + row) * K + kc + ko;
            #pragma unroll
            for (int u = 0; u < 4; ++u)
                Bs[row][(ko >> 1) + u] =
                    half2_t{(_Float16)src[2*u], (_Float16)src[2*u+1]};
        }
        __syncthreads();
        #pragma unroll
        for (int kp = 0; kp < 16; ++kp) {
            half2_t av[8], bv[4];
            #pragma unroll
            for (int r = 0; r < 8; ++r) av[r] = As[mt*8 + r][kp];
            #pragma unroll
            for (int c = 0; c < 4; ++c) bv[c] = Bs[nt*4 + c][kp];
            #pragma unroll
            for (int r = 0; r < 8; ++r)
                #pragma unroll
                for (int c = 0; c < 4; ++c)
                    acc[r][c] = dot2f(av[r], bv[c], acc[r][c]);
        }
        __syncthreads();
    }
    #pragma unroll
    for (int r = 0; r < 8; ++r) {
        const int m = m0 + mt*8 + r;
        #pragma unroll
        for (int c = 0; c < 4; ++c) {
            const int n = n0 + nt*4 + c;
            float b = bias1[n] + ((bias2 && n < lim) ? bias2[n] : 0.f);
            Cout[(size_t)m * N + n] = (CT)(acc[r][c] + b);
        }
    }
}

// ---------------------------------------------------------------------------
// MFMA GRU scan. 16 WGs x 4 batches, 512 threads (8 waves, 2/SIMD ->
// 256 unified regs/wave). A-fragments (48 x half8 = 192 regs of W_hh) are
// PINNED as opaque register values via asm("" : "+v") after init — R2/R3
// showed the compiler otherwise rematerializes them every step (reload +
// cvt ≈ 1000 VALU instr/wave/step, the entire 8 ms). Remat is impossible
// on a volatile-asm-defined value; live set ~250 <= 256 so no spill.
// One LDS-only barrier per step (raw lgkmcnt(0); s_barrier): hout stores
// and gx prefetch (reloaded into the same 12 regs one step ahead) stay
// in flight across it.
// ---------------------------------------------------------------------------
__global__ __launch_bounds__(512, 2)
void gru_scan_mfma(const _Float16* __restrict__ gx,   // [B,T,768]
                   const float* __restrict__ Whh,     // [768,256]
                   const float* __restrict__ bhh,     // [768]
                   _Float16* __restrict__ hout)       // [B,T,256]
{
    const int tid  = threadIdx.x;
    const int w    = tid >> 6;        // wave 0..7
    const int lane = tid & 63;
    const int bl   = lane & 15;       // MFMA row-in-tile (A) / batch col (B,D)
    const int q    = lane >> 4;       // quad
    const int grp  = blockIdx.x;      // 0..15
    const bool act = (bl < 4);
    const int batch = grp * 4 + (bl & 3);

    // --- stationary A fragments: lane holds W[g*256 + (2w+ti)*16 + bl][kb*32+q*8 ..+8]
    half8_t A[2][3][8];
    #pragma unroll
    for (int ti = 0; ti < 2; ++ti) {
        const int I = 2*w + ti;
        #pragma unroll
        for (int g = 0; g < 3; ++g) {
            const float* rowp = Whh + (size_t)(g*256 + I*16 + bl) * HH;
            #pragma unroll
            for (int kb = 0; kb < 8; ++kb) {
                const float* p = rowp + kb*32 + q*8;
                half8_t a;
                #pragma unroll
                for (int e = 0; e < 8; ++e) a[e] = (_Float16)p[e];
                A[ti][g][kb] = a;
            }
        }
    }
    // PIN: make each fragment an opaque, unrematerializable register value.
    #pragma unroll
    for (int ti = 0; ti < 2; ++ti)
        #pragma unroll
        for (int g = 0; g < 3; ++g)
            #pragma unroll
            for (int kb = 0; kb < 8; ++kb)
                asm volatile("" : "+v"(A[ti][g][kb]));

    // b_hh for n-gate rows of this lane, packed f16 (2 regs)
    half4_t bhn2[2];
    #pragma unroll
    for (int ti = 0; ti < 2; ++ti) {
        half4_t v;
        #pragma unroll
        for (int p = 0; p < 4; ++p)
            v[p] = (_Float16)bhh[512 + (2*w + ti)*16 + 4*q + p];
        bhn2[ti] = v;
    }

    // h double buffer: [buf][batch(4)][272 f16] (272 = 17*16 -> <=2-way bank alias)
    __shared__ alignas(16) _Float16 h2[2][4][272];
    for (int idx = tid; idx < 2*4*272; idx += 512) (&h2[0][0][0])[idx] = (_Float16)0.f;

    half4_t hprev[2] = {half4_t{0,0,0,0}, half4_t{0,0,0,0}};

    const _Float16* gp = gx + (size_t)batch * TT * G3 + (2*w)*16 + 4*q;
    _Float16* hp = hout + (size_t)batch * TT * HH + (2*w)*16 + 4*q;

    // prefetch gx for step 0
    half4_t gr[2], gz[2], gn[2];
    #pragma unroll
    for (int ti = 0; ti < 2; ++ti) {
        gr[ti] = *(const half4_t*)(gp + ti*16);
        gz[ti] = *(const half4_t*)(gp + 256 + ti*16);
        gn[ti] = *(const half4_t*)(gp + 512 + ti*16);
    }
    gp += G3;

    __syncthreads();   // h2 zeros visible

    for (int t = 0; t < TT; ++t) {
        const int cur = t & 1, nxt = cur ^ 1;

        // MFMA phase: 48 MFMAs/wave, B = h broadcast from LDS
        f32x4 acc[2][3];
        #pragma unroll
        for (int ti = 0; ti < 2; ++ti)
            #pragma unroll
            for (int g = 0; g < 3; ++g)
                acc[ti][g] = f32x4{0.f, 0.f, 0.f, 0.f};
        #pragma unroll
        for (int kb = 0; kb < 8; ++kb) {
            half8_t Bf = *(const half8_t*)&h2[cur][bl & 3][kb*32 + q*8];
            #pragma unroll
            for (int ti = 0; ti < 2; ++ti)
                #pragma unroll
                for (int g = 0; g < 3; ++g)
                    acc[ti][g] = __builtin_amdgcn_mfma_f32_16x16x32_f16(
                        A[ti][g][kb], Bf, acc[ti][g], 0, 0, 0);
        }

        // epilogue: in-lane gate math (D: col=lane&15=batch, row=q*4+reg)
        #pragma unroll
        for (int ti = 0; ti < 2; ++ti) {
            half4_t hh;
            #pragma unroll
            for (int p = 0; p < 4; ++p) {
                const float xr = (float)gr[ti][p] + acc[ti][0][p];   // b_ih+b_hh folded
                const float xz = (float)gz[ti][p] + acc[ti][1][p];   // b_ih+b_hh folded
                const float qn = acc[ti][2][p] + (float)bhn2[ti][p];
                const float r  = 1.f / (1.f + __expf(-xr));
                const float z  = 1.f / (1.f + __expf(-xz));
                const float e  = __expf(2.f * ((float)gn[ti][p] + r * qn));
                const float n  = 1.f - 2.f / (e + 1.f);
                const float hnew = (1.f - z) * n + z * (float)hprev[ti][p];
                hprev[ti][p] = (_Float16)hnew;
                hh[p] = (_Float16)hnew;
            }
            if (act) {
                const int row = (2*w + ti)*16 + 4*q;
                *(half4_t*)&h2[nxt][bl][row] = hh;      // LDS (lgkm)
                *(half4_t*)(hp + ti*16) = hh;           // global store, not waited
            }
        }
        hp += HH;

        // reload gx for step t+1 into the SAME registers (after last use).
        #pragma unroll
        for (int ti = 0; ti < 2; ++ti) {
            gr[ti] = *(const half4_t*)(gp + ti*16);
            gz[ti] = *(const half4_t*)(gp + 256 + ti*16);
            gn[ti] = *(const half4_t*)(gp + 512 + ti*16);
        }
        gp += G3;

        // LDS-only barrier: do NOT drain vmcnt (stores + gx prefetch fly free)
        asm volatile("s_waitcnt lgkmcnt(0)\n\ts_barrier" ::: "memory");
    }
}

// ---------------------------------------------------------------------------
extern "C" void kernel_launch(void* const* d_in, const int* in_sizes, int n_in,
                              void* d_out, int out_size, void* d_ws, size_t ws_size,
                              hipStream_t stream) {
    const float* x    = (const float*)d_in[0];
    const float* Wih0 = (const float*)d_in[1];
    const float* Whh0 = (const float*)d_in[2];
    const float* bih0 = (const float*)d_in[3];
    const float* bhh0 = (const float*)d_in[4];
    const float* Wih1 = (const float*)d_in[5];
    const float* Whh1 = (const float*)d_in[6];
    const float* bih1 = (const float*)d_in[7];
    const float* bhh1 = (const float*)d_in[8];
    const float* fcw  = (const float*)d_in[9];
    const float* fcb  = (const float*)d_in[10];
    float* out = (float*)d_out;

    _Float16* gxbuf = (_Float16*)d_ws;
    _Float16* hbuf  = (_Float16*)((char*)d_ws + (size_t)MTOT * G3 * sizeof(_Float16));

    const dim3 blk(256);
    // 1) gx0 = x @ W_ih0^T + (b_ih0 + b_hh0 for r/z rows)
    gemm_bt<float, _Float16><<<dim3(G3/64, MTOT/128), blk, 0, stream>>>(
        x, Wih0, bih0, bhh0, 512, gxbuf, MTOT, G3, II);
    // 2) scan layer 0 -> h0
    gru_scan_mfma<<<dim3(16), dim3(512), 0, stream>>>(gxbuf, Whh0, bhh0, hbuf);
    // 3) gx1 = h0 @ W_ih1^T + (b_ih1 + b_hh1 for r/z rows)
    gemm_bt<_Float16, _Float16><<<dim3(G3/64, MTOT/128), blk, 0, stream>>>(
        hbuf, Wih1, bih1, bhh1, 512, gxbuf, MTOT, G3, HH);
    // 4) scan layer 1 -> h1
    gru_scan_mfma<<<dim3(16), dim3(512), 0, stream>>>(gxbuf, Whh1, bhh1, hbuf);
    // 5) out = h1 @ fc_w^T + fc_b
    gemm_bt<_Float16, float><<<dim3(CC/64, MTOT/128), blk, 0, stream>>>(
        hbuf, fcw, fcb, nullptr, 0, out, MTOT, CC, HH);
}

// Round 5
// 16326.573 us; speedup vs baseline: 1.0545x; 1.0005x over previous
//
#include <hip/hip_runtime.h>

typedef _Float16 half2_t __attribute__((ext_vector_type(2)));
typedef _Float16 half4_t __attribute__((ext_vector_type(4)));
typedef _Float16 half8_t __attribute__((ext_vector_type(8)));
typedef float f32x4 __attribute__((ext_vector_type(4)));

#define BB 64
#define TT 2048
#define II 128
#define HH 256
#define CC 64
#define G3 (3*HH)          // 768
#define MTOT (BB*TT)       // 131072

static __device__ __forceinline__ float dot2f(half2_t a, half2_t b, float c) {
#if __has_builtin(__builtin_amdgcn_fdot2)
    return __builtin_amdgcn_fdot2(a, b, c, false);
#else
    return c + (float)a[0]*(float)b[0] + (float)a[1]*(float)b[1];
#endif
}

// ---------------------------------------------------------------------------
// Tiled GEMM: C[M,N] = A[M,K] @ W[N,K]^T + bias1 (+ bias2 for n<lim).
// f16 dot2 inner, fp32 accum. Unchanged (verified R1-R4).
// ---------------------------------------------------------------------------
template<typename AT, typename CT>
__global__ __launch_bounds__(256, 2)
void gemm_bt(const AT* __restrict__ A, const float* __restrict__ W,
             const float* __restrict__ bias1, const float* __restrict__ bias2,
             int lim, CT* __restrict__ Cout, int M, int N, int K)
{
    __shared__ half2_t As[128][17];
    __shared__ half2_t Bs[64][17];
    const int tid = threadIdx.x;
    const int m0 = blockIdx.y * 128;
    const int n0 = blockIdx.x * 64;
    const int mt = tid & 15;
    const int nt = tid >> 4;
    float acc[8][4] = {};

    for (int kc = 0; kc < K; kc += 32) {
        {
            const int row = tid >> 1;
            const int ko  = (tid & 1) * 16;
            const AT* src = A + (size_t)(m0 + row) * K + kc + ko;
            #pragma unroll
            for (int u = 0; u < 8; ++u)
                As[row][(ko >> 1) + u] =
                    half2_t{(_Float16)(float)src[2*u], (_Float16)(float)src[2*u+1]};
        }
        {
            const int row = tid >> 2;
            const int ko  = (tid & 3) * 8;
            const float* src = W + (size_t)(n0 + row) * K + kc + ko;
            #pragma unroll
            for (int u = 0; u < 4; ++u)
                Bs[row][(ko >> 1) + u] =
                    half2_t{(_Float16)src[2*u], (_Float16)src[2*u+1]};
        }
        __syncthreads();
        #pragma unroll
        for (int kp = 0; kp < 16; ++kp) {
            half2_t av[8], bv[4];
            #pragma unroll
            for (int r = 0; r < 8; ++r) av[r] = As[mt*8 + r][kp];
            #pragma unroll
            for (int c = 0; c < 4; ++c) bv[c] = Bs[nt*4 + c][kp];
            #pragma unroll
            for (int r = 0; r < 8; ++r)
                #pragma unroll
                for (int c = 0; c < 4; ++c)
                    acc[r][c] = dot2f(av[r], bv[c], acc[r][c]);
        }
        __syncthreads();
    }
    #pragma unroll
    for (int r = 0; r < 8; ++r) {
        const int m = m0 + mt*8 + r;
        #pragma unroll
        for (int c = 0; c < 4; ++c) {
            const int n = n0 + nt*4 + c;
            float b = bias1[n] + ((bias2 && n < lim) ? bias2[n] : 0.f);
            Cout[(size_t)m * N + n] = (CT)(acc[r][c] + b);
        }
    }
}

// ---------------------------------------------------------------------------
// MFMA GRU scan. 16 WGs x 4 batches, 512 threads (8 waves).
// REGISTER BUDGET (the R2-R4 lesson): __launch_bounds__(512, 2) was taken
// as min 2 BLOCKS/CU (CUDA semantics) -> 16 waves/CU -> 128-reg cap ->
// the 192-reg stationary W_hh fragment set could never be resident and the
// compiler rematerialized it every step (~1000 VALU instr/wave/step = the
// whole 8 ms). Plain __launch_bounds__(512) caps at 2048/8 = 256 regs/wave,
// which fits the ~253-reg live set. asm "+v" pins keep the frags
// unrematerializable. One LDS-only barrier per step (raw lgkmcnt(0);
// s_barrier): hout stores and the gx prefetch (reloaded into the same 12
// regs one step ahead) stay in flight across it.
// ---------------------------------------------------------------------------
__global__ __launch_bounds__(512)
void gru_scan_mfma(const _Float16* __restrict__ gx,   // [B,T,768]
                   const float* __restrict__ Whh,     // [768,256]
                   const float* __restrict__ bhh,     // [768]
                   _Float16* __restrict__ hout)       // [B,T,256]
{
    const int tid  = threadIdx.x;
    const int w    = tid >> 6;        // wave 0..7
    const int lane = tid & 63;
    const int bl   = lane & 15;       // MFMA row-in-tile (A) / batch col (B,D)
    const int q    = lane >> 4;       // quad
    const int grp  = blockIdx.x;      // 0..15
    const bool act = (bl < 4);
    const int batch = grp * 4 + (bl & 3);

    // --- stationary A fragments: lane holds W[g*256 + (2w+ti)*16 + bl][kb*32+q*8 ..+8]
    half8_t A[2][3][8];
    #pragma unroll
    for (int ti = 0; ti < 2; ++ti) {
        const int I = 2*w + ti;
        #pragma unroll
        for (int g = 0; g < 3; ++g) {
            const float* rowp = Whh + (size_t)(g*256 + I*16 + bl) * HH;
            #pragma unroll
            for (int kb = 0; kb < 8; ++kb) {
                const float* p = rowp + kb*32 + q*8;
                half8_t a;
                #pragma unroll
                for (int e = 0; e < 8; ++e) a[e] = (_Float16)p[e];
                A[ti][g][kb] = a;
            }
        }
    }
    // PIN: opaque, unrematerializable register values (now within budget).
    #pragma unroll
    for (int ti = 0; ti < 2; ++ti)
        #pragma unroll
        for (int g = 0; g < 3; ++g)
            #pragma unroll
            for (int kb = 0; kb < 8; ++kb)
                asm volatile("" : "+v"(A[ti][g][kb]));

    // b_hh for n-gate rows of this lane, packed f16 (2 regs)
    half4_t bhn2[2];
    #pragma unroll
    for (int ti = 0; ti < 2; ++ti) {
        half4_t v;
        #pragma unroll
        for (int p = 0; p < 4; ++p)
            v[p] = (_Float16)bhh[512 + (2*w + ti)*16 + 4*q + p];
        bhn2[ti] = v;
    }

    // h double buffer: [buf][batch(4)][272 f16] (272 = 17*16 -> <=2-way bank alias)
    __shared__ alignas(16) _Float16 h2[2][4][272];
    for (int idx = tid; idx < 2*4*272; idx += 512) (&h2[0][0][0])[idx] = (_Float16)0.f;

    half4_t hprev[2] = {half4_t{0,0,0,0}, half4_t{0,0,0,0}};

    const _Float16* gp = gx + (size_t)batch * TT * G3 + (2*w)*16 + 4*q;
    _Float16* hp = hout + (size_t)batch * TT * HH + (2*w)*16 + 4*q;

    // prefetch gx for step 0
    half4_t gr[2], gz[2], gn[2];
    #pragma unroll
    for (int ti = 0; ti < 2; ++ti) {
        gr[ti] = *(const half4_t*)(gp + ti*16);
        gz[ti] = *(const half4_t*)(gp + 256 + ti*16);
        gn[ti] = *(const half4_t*)(gp + 512 + ti*16);
    }
    gp += G3;

    __syncthreads();   // h2 zeros visible

    for (int t = 0; t < TT; ++t) {
        const int cur = t & 1, nxt = cur ^ 1;

        // MFMA phase: 48 MFMAs/wave, B = h broadcast from LDS
        f32x4 acc[2][3];
        #pragma unroll
        for (int ti = 0; ti < 2; ++ti)
            #pragma unroll
            for (int g = 0; g < 3; ++g)
                acc[ti][g] = f32x4{0.f, 0.f, 0.f, 0.f};
        #pragma unroll
        for (int kb = 0; kb < 8; ++kb) {
            half8_t Bf = *(const half8_t*)&h2[cur][bl & 3][kb*32 + q*8];
            #pragma unroll
            for (int ti = 0; ti < 2; ++ti)
                #pragma unroll
                for (int g = 0; g < 3; ++g)
                    acc[ti][g] = __builtin_amdgcn_mfma_f32_16x16x32_f16(
                        A[ti][g][kb], Bf, acc[ti][g], 0, 0, 0);
        }

        // epilogue: in-lane gate math (D: col=lane&15=batch, row=q*4+reg)
        #pragma unroll
        for (int ti = 0; ti < 2; ++ti) {
            half4_t hh;
            #pragma unroll
            for (int p = 0; p < 4; ++p) {
                const float xr = (float)gr[ti][p] + acc[ti][0][p];   // b_ih+b_hh folded
                const float xz = (float)gz[ti][p] + acc[ti][1][p];   // b_ih+b_hh folded
                const float qn = acc[ti][2][p] + (float)bhn2[ti][p];
                const float r  = 1.f / (1.f + __expf(-xr));
                const float z  = 1.f / (1.f + __expf(-xz));
                const float e  = __expf(2.f * ((float)gn[ti][p] + r * qn));
                const float n  = 1.f - 2.f / (e + 1.f);
                const float hnew = (1.f - z) * n + z * (float)hprev[ti][p];
                hprev[ti][p] = (_Float16)hnew;
                hh[p] = (_Float16)hnew;
            }
            if (act) {
                const int row = (2*w + ti)*16 + 4*q;
                *(half4_t*)&h2[nxt][bl][row] = hh;      // LDS (lgkm)
                *(half4_t*)(hp + ti*16) = hh;           // global store, not waited
            }
        }
        hp += HH;

        // reload gx for step t+1 into the SAME registers (after last use).
        #pragma unroll
        for (int ti = 0; ti < 2; ++ti) {
            gr[ti] = *(const half4_t*)(gp + ti*16);
            gz[ti] = *(const half4_t*)(gp + 256 + ti*16);
            gn[ti] = *(const half4_t*)(gp + 512 + ti*16);
        }
        gp += G3;

        // LDS-only barrier: do NOT drain vmcnt (stores + gx prefetch fly free)
        asm volatile("s_waitcnt lgkmcnt(0)\n\ts_barrier" ::: "memory");
    }
}

// ---------------------------------------------------------------------------
extern "C" void kernel_launch(void* const* d_in, const int* in_sizes, int n_in,
                              void* d_out, int out_size, void* d_ws, size_t ws_size,
                              hipStream_t stream) {
    const float* x    = (const float*)d_in[0];
    const float* Wih0 = (const float*)d_in[1];
    const float* Whh0 = (const float*)d_in[2];
    const float* bih0 = (const float*)d_in[3];
    const float* bhh0 = (const float*)d_in[4];
    const float* Wih1 = (const float*)d_in[5];
    const float* Whh1 = (const float*)d_in[6];
    const float* bih1 = (const float*)d_in[7];
    const float* bhh1 = (const float*)d_in[8];
    const float* fcw  = (const float*)d_in[9];
    const float* fcb  = (const float*)d_in[10];
    float* out = (float*)d_out;

    _Float16* gxbuf = (_Float16*)d_ws;
    _Float16* hbuf  = (_Float16*)((char*)d_ws + (size_t)MTOT * G3 * sizeof(_Float16));

    const dim3 blk(256);
    // 1) gx0 = x @ W_ih0^T + (b_ih0 + b_hh0 for r/z rows)
    gemm_bt<float, _Float16><<<dim3(G3/64, MTOT/128), blk, 0, stream>>>(
        x, Wih0, bih0, bhh0, 512, gxbuf, MTOT, G3, II);
    // 2) scan layer 0 -> h0
    gru_scan_mfma<<<dim3(16), dim3(512), 0, stream>>>(gxbuf, Whh0, bhh0, hbuf);
    // 3) gx1 = h0 @ W_ih1^T + (b_ih1 + b_hh1 for r/z rows)
    gemm_bt<_Float16, _Float16><<<dim3(G3/64, MTOT/128), blk, 0, stream>>>(
        hbuf, Wih1, bih1, bhh1, 512, gxbuf, MTOT, G3, HH);
    // 4) scan layer 1 -> h1
    gru_scan_mfma<<<dim3(16), dim3(512), 0, stream>>>(gxbuf, Whh1, bhh1, hbuf);
    // 5) out = h1 @ fc_w^T + fc_b
    gemm_bt<_Float16, float><<<dim3(CC/64, MTOT/128), blk, 0, stream>>>(
        hbuf, fcw, fcb, nullptr, 0, out, MTOT, CC, HH);
}